// Round 1
// baseline (179.563 us; speedup 1.0000x reference)
//
#include <hip/hip_runtime.h>
#include <stdint.h>

// 3x3 conv s1 p1, NCHW fp32, 64->128 ch, 16x112x112.
// Implicit GEMM on bf16 MFMA with NHWC bf16 x-repack in d_ws:
//   prep:  x (NCHW fp32) -> x_t[(n*12544+p)*64+ic] bf16 ; w -> Wt[tap][oc][ic] bf16 ; 128B zero block
//   conv:  per block 128oc x 128px tile. X union (354 pixel rows, 45.4KB) staged ONCE;
//          weights double-buffered 16KB/tap with prefetch-before-compute; ONE barrier/tap.
//          Boundary pixels: fragment row redirected to an LDS zero row (1 cndmask per (tap,ni)).

#define HW     112
#define PIX    12544
#define ICN    64
#define OCN    128
#define TILEP  128
#define PTILES 98
#define NBLK   1568
#define NIMG   16

#define XT_BYTES   (NIMG * PIX * ICN * 2)          // 25,690,112
#define WT_OFF     XT_BYTES
#define WT_BYTES   (9 * OCN * ICN * 2)             // 147,456
#define ZG_OFF     (WT_OFF + WT_BYTES)             // 128B zero block
#define XBLK       (NIMG * (PIX / 64))             // 3136 transpose blocks
#define WBLK       72                              // 72 * 1024 = 73728 weight elems

#define XU_LO      113                             // rows below p0 staged (112+1)
#define XU_DATA    354                             // p0-113 .. p0+240 inclusive
#define XU_ZROW    354                             // index of the zero row
#define XU_ROWS    355                             // data + zero row

typedef __attribute__((ext_vector_type(8))) __bf16 bf16x8;
typedef __attribute__((ext_vector_type(4))) float  f32x4;

__device__ __forceinline__ uint32_t rne_lo(float f) {
    uint32_t u = __builtin_bit_cast(uint32_t, f);
    return (u + 0x7fffu + ((u >> 16) & 1u)) >> 16;
}
__device__ __forceinline__ uint32_t pk2(float a, float b) {
    uint32_t ub = __builtin_bit_cast(uint32_t, b);
    ub = (ub + 0x7fffu + ((ub >> 16) & 1u)) & 0xffff0000u;
    return rne_lo(a) | ub;
}

__device__ __forceinline__ void load_lds16(const void* g, void* l) {
    __builtin_amdgcn_global_load_lds(
        (const __attribute__((address_space(1))) uint32_t*)g,
        (__attribute__((address_space(3))) uint32_t*)l, 16, 0, 0);
}

// ---------------- prep: x transpose+cvt, weight transpose+cvt, zero block ----------------
__global__ void __launch_bounds__(256)
prep(const float* __restrict__ x, const float* __restrict__ w, uint8_t* __restrict__ ws) {
    const int b = blockIdx.x;
    const int t = threadIdx.x;
    uint16_t* xt = (uint16_t*)ws;
    uint16_t* wt = (uint16_t*)(ws + WT_OFF);

    if (b < XBLK) {
        // 64 pixels per block; thread: pixel = t>>2, ic chunk q = t&3 (16 ic each)
        const int n  = b / (PIX / 64);
        const int p0 = (b - n * (PIX / 64)) * 64;
        const int px = t >> 2;
        const int q  = t & 3;
        const float* src = x + ((size_t)n * ICN + q * 16) * PIX + p0 + px;
        float v[16];
#pragma unroll
        for (int i = 0; i < 16; ++i) v[i] = src[(size_t)i * PIX];
        uint4 u0 = make_uint4(pk2(v[0], v[1]),  pk2(v[2], v[3]),
                              pk2(v[4], v[5]),  pk2(v[6], v[7]));
        uint4 u1 = make_uint4(pk2(v[8], v[9]),  pk2(v[10], v[11]),
                              pk2(v[12], v[13]), pk2(v[14], v[15]));
        char* dst = (char*)xt + ((size_t)(n * PIX + p0 + px)) * 128 + q * 32;
        *(uint4*)dst        = u0;
        *(uint4*)(dst + 16) = u1;
    } else {
        const int wb = b - XBLK;
#pragma unroll
        for (int k = 0; k < 4; ++k) {
            int wi = wb * 1024 + k * 256 + t;          // [0, 73728)
            int r  = wi >> 13;
            int oc = (wi >> 6) & 127;
            int ic = wi & 63;
            wt[wi] = (uint16_t)rne_lo(w[oc * 576 + ic * 9 + r]);
        }
        if (wb == 0 && t < 8) ((uint4*)(ws + ZG_OFF))[t] = make_uint4(0, 0, 0, 0);
    }
}

// ---------------- main conv ----------------
__global__ void __launch_bounds__(256)
conv_mfma(const uint8_t* __restrict__ ws, const float* __restrict__ bias,
          float* __restrict__ out) {
    __shared__ uint8_t Wb[2][16384];        // weights, double-buffered per tap
    __shared__ uint8_t Xu[XU_ROWS * 128];   // X union: 354 pixel rows + 1 zero row

    const char* xt = (const char*)ws;
    const char* wt = (const char*)(ws + WT_OFF);
    const char* zg = (const char*)(ws + ZG_OFF);

    const int t = threadIdx.x;
    const int b = blockIdx.x;
    const int n_img = b / PTILES;
    const int p0 = (b - n_img * PTILES) * TILEP;

    const int lane = t & 63;
    const int wave = t >> 6;
    const int lr = lane & 15;
    const int lq = lane >> 4;
    const int oc_base = (wave & 1) * 64;
    const int px_base = (wave >> 1) * 64;

    // ---- staging geometry: pass covers 32 rows; row = pass*32 + (t>>3); chunk = t&7 (XOR-swizzled)
    const int rowB  = t >> 3;                        // 0..31 (= wave*8 + lane>>3)
    const int cswz8 = ((t & 7) ^ (rowB & 7)) * 16;   // row&7 == rowB&7 (pass*32 ≡ 0 mod 8)
    const char* zaddr = zg + (t & 7) * 16;

    // ---- stage X union once: rows r=0..353 hold pixel p0-113+r (OOB -> zero block) ----
    const char* xrow0 = xt + ((ptrdiff_t)(n_img * PIX + p0 - XU_LO)) * 128 + cswz8;
#pragma unroll
    for (int r2 = 0; r2 < 11; ++r2) {
        int r = r2 * 32 + rowB;
        int p = p0 - XU_LO + r;
        const char* gp = ((unsigned)p < PIX) ? (xrow0 + (ptrdiff_t)r * 128) : zaddr;
        load_lds16(gp, (char*)Xu + r2 * 4096 + wave * 1024);
    }
    if (t < 16) {                                    // tail rows 352,353 (2 rows = 16 lanes)
        int r = 352 + (t >> 3);
        int p = p0 - XU_LO + r;
        const char* gp = ((unsigned)p < PIX) ? (xrow0 + (ptrdiff_t)r * 128) : zaddr;
        load_lds16(gp, (char*)Xu + 352 * 128);
    }
    if (t < 8) *(uint4*)((char*)Xu + XU_ZROW * 128 + t * 16) = make_uint4(0, 0, 0, 0);

    // ---- stage weights tap 0 -> Wb[0] ----
    const char* wsrc = wt + rowB * 128 + cswz8;
#pragma unroll
    for (int r2 = 0; r2 < 4; ++r2)
        load_lds16(wsrc + r2 * 4096, (char*)Wb + r2 * 4096 + wave * 1024);

    // ---- per-ni pixel (h,w) and Xu row base ----
    int hh[4], wwp[4], rb[4];
#pragma unroll
    for (int ni = 0; ni < 4; ++ni) {
        int p = p0 + px_base + ni * 16 + lr;
        int h = p / HW;
        hh[ni]  = h;
        wwp[ni] = p - h * HW;
        rb[ni]  = px_base + ni * 16 + lr + XU_LO;
    }

    f32x4 acc[4][4];
    {
        f32x4 z = {0.f, 0.f, 0.f, 0.f};
#pragma unroll
        for (int i = 0; i < 4; ++i)
#pragma unroll
            for (int j = 0; j < 4; ++j) acc[i][j] = z;
    }

    __syncthreads();   // drains all staging DMA (vmcnt(0)+lgkmcnt(0)) + barrier

#pragma unroll
    for (int tap = 0; tap < 9; ++tap) {
        const int dy = tap / 3 - 1;
        const int dx = tap - (tap / 3) * 3 - 1;
        const int roff = dy * HW + dx;

        // prefetch next tap's weights into the other buffer (read last at tap-1,
        // everyone passed that tap's barrier, so no reader remains)
        if (tap < 8) {
#pragma unroll
            for (int r2 = 0; r2 < 4; ++r2)
                load_lds16(wsrc + (tap + 1) * 16384 + r2 * 4096,
                           (char*)Wb + ((tap + 1) & 1) * 16384 + r2 * 4096 + wave * 1024);
        }

        // boundary handling: redirect invalid rows to the zero row
        int ro[4];
#pragma unroll
        for (int ni = 0; ni < 4; ++ni) {
            bool ok = ((unsigned)(hh[ni] + dy) < HW) & ((unsigned)(wwp[ni] + dx) < HW);
            ro[ni] = ok ? (rb[ni] + roff) : XU_ZROW;
        }

        const char* wbase = (const char*)Wb + (tap & 1) * 16384;
#pragma unroll
        for (int kh = 0; kh < 2; ++kh) {
            const int cc = kh * 4 + lq;
            bf16x8 a_frag[4], b_frag[4];
#pragma unroll
            for (int mi = 0; mi < 4; ++mi) {
                int R = oc_base + mi * 16 + lr;
                a_frag[mi] = *(const bf16x8*)(wbase + R * 128 + ((cc ^ (R & 7)) * 16));
            }
#pragma unroll
            for (int ni = 0; ni < 4; ++ni)
                b_frag[ni] = *(const bf16x8*)((const char*)Xu + ro[ni] * 128
                                              + ((cc ^ (ro[ni] & 7)) * 16));
#pragma unroll
            for (int mi = 0; mi < 4; ++mi)
#pragma unroll
                for (int ni = 0; ni < 4; ++ni)
                    acc[mi][ni] = __builtin_amdgcn_mfma_f32_16x16x32_bf16(
                        a_frag[mi], b_frag[ni], acc[mi][ni], 0, 0, 0);
        }
        // one barrier per tap: implicit vmcnt(0) drains the prefetch (covered by
        // this tap's 16 ds_read + 32 MFMA), barrier releases next tap's reads.
        if (tap < 8) __syncthreads();
    }

    // ---- epilogue: D col = lane&15 -> pixel, row = lq*4+reg -> oc (validated R1)
#pragma unroll
    for (int mi = 0; mi < 4; ++mi) {
#pragma unroll
        for (int rg = 0; rg < 4; ++rg) {
            const int oc = oc_base + mi * 16 + lq * 4 + rg;
            const float bb = bias[oc];
            float* orow = out + ((size_t)n_img * OCN + oc) * PIX + p0 + px_base + lr;
#pragma unroll
            for (int ni = 0; ni < 4; ++ni)
                orow[ni * 16] = acc[mi][ni][rg] + bb;
        }
    }
}

extern "C" void kernel_launch(void* const* d_in, const int* in_sizes, int n_in,
                              void* d_out, int out_size, void* d_ws, size_t ws_size,
                              hipStream_t stream) {
    const float* x    = (const float*)d_in[0];
    const float* w    = (const float*)d_in[1];
    const float* bias = (const float*)d_in[2];
    float* out = (float*)d_out;
    uint8_t* ws = (uint8_t*)d_ws;   // needs ZG_OFF + 128 = 25,837,696 bytes

    prep<<<XBLK + WBLK, 256, 0, stream>>>(x, w, ws);
    conv_mfma<<<NBLK, 256, 0, stream>>>(ws, bias, out);
}